// Round 3
// baseline (613.993 us; speedup 1.0000x reference)
//
#include <hip/hip_runtime.h>
#include <hip/hip_bf16.h>

// Problem constants
#define MROW 8192   // BATCH
#define DIMK 4096   // DIM (= K of both GEMMs)
#define NCOL 4096   // N_HEADS*HIDDEN = DIM
#define HID  256
#define NH   16
#define SEQL 4096

// GEMM tile geometry: 256x256 tile, BK=32, 8 waves (2M x 4N), ring-of-4 LDS buffers
#define BM 256
#define BN 256
#define BK 32
#define NKT (DIMK / BK)        // 128 K-tiles
#define TILEB (BM * BK * 2)    // 16384 B per A- or B- K-tile
#define LDS_TOTAL (8 * TILEB)  // 131072 B

typedef __attribute__((ext_vector_type(8))) short short8;
typedef __attribute__((ext_vector_type(4))) float f32x4;

__device__ inline ushort f2bf(float f) {
  unsigned u = __float_as_uint(f);
  u += 0x7FFF + ((u >> 16) & 1);   // RNE
  return (ushort)(u >> 16);
}

__device__ inline void gload16(const void* g, void* l) {
  __builtin_amdgcn_global_load_lds(
      (const __attribute__((address_space(1))) void*)g,
      (__attribute__((address_space(3))) void*)l, 16, 0, 0);
}

// fp32 -> bf16, 8 elements/thread, grid-stride
__global__ void cvt_f32_bf16(const float* __restrict__ s, ushort* __restrict__ d, long n8) {
  long stride = (long)gridDim.x * blockDim.x;
  for (long i = (long)blockIdx.x * blockDim.x + threadIdx.x; i < n8; i += stride) {
    const float4* s4 = (const float4*)(s + i * 8);
    float4 a = s4[0], b = s4[1];
    ushort r[8] = {f2bf(a.x), f2bf(a.y), f2bf(a.z), f2bf(a.w),
                   f2bf(b.x), f2bf(b.y), f2bf(b.z), f2bf(b.w)};
    *(uint4*)(d + i * 8) = *(const uint4*)r;
  }
}

// per-output-column coefficients for the GEMM1 epilogue
__global__ void coef_kernel(const float* __restrict__ mix_w, const float* __restrict__ mix_b,
                            const float* __restrict__ decay_value, const float* __restrict__ proj_b,
                            const int* __restrict__ index_p,
                            float* __restrict__ wv, float* __restrict__ cc, float* __restrict__ pb2) {
  int n = blockIdx.x * blockDim.x + threadIdx.x;   // 0..4095
  if (n >= NCOL) return;
  int h = n >> 8;
  int idx = *index_p;
  float w  = mix_w[h * SEQL + idx];
  float bb = mix_b[h * SEQL + idx];
  float dv = fminf(fmaxf(decay_value[h], 0.9f), 1.0f);
  float decay = powf(dv, 0.125f);                  // 1/DECAY_CONSTANT (=8)
  float coef = (h < NH / 2) ? w * decay : decay;
  wv[n]  = w;
  cc[n]  = coef;
  pb2[n] = w * proj_b[n] + bb;
}

// stage one 256x32 bf16 K-tile (A or B) into a linear LDS buffer with
// inverse-swizzled global source (rule 21: linear dest + pre-swizzled src).
// Swizzle: 16B-column c' = c ^ ((row>>1)&3)  -> 2-way bank aliasing on ds_read (free, m136).
__device__ inline void stage(const ushort* __restrict__ G, int k0, char* lbase, int tid) {
#pragma unroll
  for (int j = 0; j < 2; ++j) {
    int off = j * 8192 + tid * 16;      // linear LDS byte offset (wave-uniform base + lane*16)
    int row = off >> 6;                 // 64 B per row (32 bf16)
    int c   = (off >> 4) & 3;
    int cs  = c ^ ((row >> 1) & 3);
    gload16(G + (size_t)row * DIMK + k0 + cs * 8, lbase + off);
  }
}

// read one MFMA fragment (16B/lane) from a swizzled K-tile
__device__ inline short8 frag(const char* base, int row, int c) {
  int cs = c ^ ((row >> 1) & 3);
  return *(const short8*)(base + row * 64 + cs * 16);
}

// C = A(MxK) * B^T(NxK), bf16. Deep-pipelined: 2 phases/K-tile, counted vmcnt(8),
// prefetch lead 3 K-tiles into a 4-buffer LDS ring. Raw s_barrier (no sched pinning
// except one fence per K-tile at the WAR-hazard boundary). EPI==1: mix -> bf16;
// EPI==0: +out_b -> f32.
template <int EPI>
__global__ __launch_bounds__(512, 2) void gemm256(
    const ushort* __restrict__ A, const ushort* __restrict__ B,
    float* __restrict__ outf, ushort* __restrict__ outh,
    const float* __restrict__ cache, const float* __restrict__ wv,
    const float* __restrict__ cc, const float* __restrict__ pb2,
    const float* __restrict__ outb) {
  extern __shared__ __align__(16) char smem[];
  char* const Abufs = smem;                 // 4 x 16KB
  char* const Bbufs = smem + 4 * TILEB;     // 4 x 16KB

  const int tid  = threadIdx.x;
  const int wid  = tid >> 6;
  const int lane = tid & 63;
  const int wr = wid >> 2;       // 0..1  (M)
  const int wc = wid & 3;        // 0..3  (N)
  const int r16 = lane & 15;
  const int cq  = lane >> 4;     // 16B column block 0..3

  // XCD-bijective block swizzle (grid = 512, 512 % 8 == 0)
  const int bid = blockIdx.x;
  const int swz = (bid & 7) * 64 + (bid >> 3);
  const int bm = swz >> 4, bn = swz & 15;   // 32 x 16 tiles
  const int m0 = bm * BM, n0 = bn * BN;

  const ushort* Ag = A + (size_t)m0 * DIMK;
  const ushort* Bg = B + (size_t)n0 * DIMK;

  f32x4 acc[8][4] = {};

  // prologue: stage K-tiles 0,1,2 (12 loads/thread); wait until kt0 landed (8 in flight)
#pragma unroll
  for (int kt = 0; kt < 3; ++kt) {
    stage(Ag, kt * BK, Abufs + kt * TILEB, tid);
    stage(Bg, kt * BK, Bbufs + kt * TILEB, tid);
  }
  asm volatile("s_waitcnt vmcnt(8)" ::: "memory");
  __builtin_amdgcn_s_barrier();
  __builtin_amdgcn_sched_barrier(0);

  for (int kt = 0; kt < NKT; ++kt) {
    char* Ab = Abufs + (kt & 3) * TILEB;
    char* Bb = Bbufs + (kt & 3) * TILEB;
    const int  ktp = kt + 3;
    const bool do_st = ktp < NKT;

    short8 bfr[4], afr[4];

    // ---- phase 0: read B frags + A frags (rows 0..63 of wave tile); stage A of kt+3
#pragma unroll
    for (int ni = 0; ni < 4; ++ni)
      bfr[ni] = frag(Bb, wc * 64 + ni * 16 + r16, cq);
#pragma unroll
    for (int mi = 0; mi < 4; ++mi)
      afr[mi] = frag(Ab, wr * 128 + mi * 16 + r16, cq);
    if (do_st) stage(Ag, ktp * BK, Abufs + (ktp & 3) * TILEB, tid);
    __builtin_amdgcn_s_barrier();
    asm volatile("s_waitcnt lgkmcnt(0)" ::: "memory");
    __builtin_amdgcn_s_setprio(1);
#pragma unroll
    for (int mi = 0; mi < 4; ++mi)
#pragma unroll
      for (int ni = 0; ni < 4; ++ni)
        acc[mi][ni] = __builtin_amdgcn_mfma_f32_16x16x32_bf16(afr[mi], bfr[ni], acc[mi][ni], 0, 0, 0);
    __builtin_amdgcn_s_setprio(0);
    __builtin_amdgcn_s_barrier();

    // ---- phase 1: read A frags (rows 64..127); stage B of kt+3; reuse B frags
#pragma unroll
    for (int mi = 0; mi < 4; ++mi)
      afr[mi] = frag(Ab, wr * 128 + 64 + mi * 16 + r16, cq);
    if (do_st) stage(Bg, ktp * BK, Bbufs + (ktp & 3) * TILEB, tid);
    __builtin_amdgcn_s_barrier();
    asm volatile("s_waitcnt lgkmcnt(0)" ::: "memory");
    __builtin_amdgcn_s_setprio(1);
#pragma unroll
    for (int mi = 0; mi < 4; ++mi)
#pragma unroll
      for (int ni = 0; ni < 4; ++ni)
        acc[4 + mi][ni] = __builtin_amdgcn_mfma_f32_16x16x32_bf16(afr[mi], bfr[ni], acc[4 + mi][ni], 0, 0, 0);
    __builtin_amdgcn_s_setprio(0);
    // counted wait: keep 2 K-tiles (8 loads) in flight; guarantee kt+1 landed.
    if (kt < NKT - 3)       asm volatile("s_waitcnt vmcnt(8)" ::: "memory");
    else if (kt == NKT - 3) asm volatile("s_waitcnt vmcnt(4)" ::: "memory");
    else if (kt == NKT - 2) asm volatile("s_waitcnt vmcnt(0)" ::: "memory");
    __builtin_amdgcn_s_barrier();
    // single scheduling fence per K-tile: next tile's stage must not hoist above
    // this barrier (cross-wave WAR on the ring buffer it overwrites).
    __builtin_amdgcn_sched_barrier(0);
  }

  // ---- epilogue
  const int colbase = n0 + wc * 64 + r16;
  const int rowbase = m0 + wr * 128 + cq * 4;

  float wvv[4], ccv[4], pbv[4], obv[4];
#pragma unroll
  for (int ni = 0; ni < 4; ++ni) {
    int n = colbase + ni * 16;
    if (EPI == 1) { wvv[ni] = wv[n]; ccv[ni] = cc[n]; pbv[ni] = pb2[n]; }
    else          { obv[ni] = outb[n]; }
  }

#pragma unroll
  for (int am = 0; am < 8; ++am) {
    int mrow = rowbase + (am >> 2) * 64 + (am & 3) * 16;
#pragma unroll
    for (int ni = 0; ni < 4; ++ni) {
      f32x4 v = acc[am][ni];
      int n = colbase + ni * 16;
#pragma unroll
      for (int r = 0; r < 4; ++r) {
        int m = mrow + r;
        if (EPI == 1) {
          int h = n >> 8, kq = n & 255;
          float val = wvv[ni] * v[r] + ccv[ni] * cache[((size_t)h * MROW + m) * HID + kq] + pbv[ni];
          outh[(size_t)m * NCOL + n] = f2bf(val);
        } else {
          outf[(size_t)m * NCOL + n] = v[r] + obv[ni];
        }
      }
    }
  }
}

extern "C" void kernel_launch(void* const* d_in, const int* in_sizes, int n_in,
                              void* d_out, int out_size, void* d_ws, size_t ws_size,
                              hipStream_t stream) {
  const float* x      = (const float*)d_in[0];
  const float* proj_w = (const float*)d_in[1];
  const float* proj_b = (const float*)d_in[2];
  const float* mix_w  = (const float*)d_in[3];
  const float* mix_b  = (const float*)d_in[4];
  const float* decay  = (const float*)d_in[5];
  const float* cache  = (const float*)d_in[6];
  const float* out_w  = (const float*)d_in[7];
  const float* out_b  = (const float*)d_in[8];
  const int*   index  = (const int*)d_in[9];

  char* ws = (char*)d_ws;
  ushort* xb  = (ushort*)ws;                         // 8192*4096*2 = 64 MiB
  ushort* pwb = (ushort*)(ws + 67108864);            // 32 MiB
  ushort* owb = (ushort*)(ws + 100663296);           // 32 MiB
  ushort* hid = (ushort*)(ws + 134217728);           // 64 MiB
  float*  wv  = (float*)(ws + 201326592);
  float*  cc  = (float*)(ws + 201326592 + 16384);
  float*  pb2 = (float*)(ws + 201326592 + 32768);

  // allow 128 KiB dynamic LDS (host-side attribute set; not a stream op)
  hipFuncSetAttribute((const void*)&gemm256<1>, hipFuncAttributeMaxDynamicSharedMemorySize, LDS_TOTAL);
  hipFuncSetAttribute((const void*)&gemm256<0>, hipFuncAttributeMaxDynamicSharedMemorySize, LDS_TOTAL);

  hipLaunchKernelGGL(cvt_f32_bf16, dim3(2048), dim3(256), 0, stream,
                     x, xb, (long)MROW * DIMK / 8);
  hipLaunchKernelGGL(cvt_f32_bf16, dim3(1024), dim3(256), 0, stream,
                     proj_w, pwb, (long)NCOL * DIMK / 8);
  hipLaunchKernelGGL(cvt_f32_bf16, dim3(1024), dim3(256), 0, stream,
                     out_w, owb, (long)NCOL * DIMK / 8);
  hipLaunchKernelGGL(coef_kernel, dim3(16), dim3(256), 0, stream,
                     mix_w, mix_b, decay, proj_b, index, wv, cc, pb2);

  // GEMM1: hidden = mix(x @ proj_w^T) -> bf16
  hipLaunchKernelGGL((gemm256<1>), dim3((MROW / BM) * (NCOL / BN)), dim3(512), LDS_TOTAL, stream,
                     xb, pwb, nullptr, hid, cache, wv, cc, pb2, nullptr);
  // GEMM2: out = hidden @ out_w^T + out_b -> f32
  hipLaunchKernelGGL((gemm256<0>), dim3((MROW / BM) * (NCOL / BN)), dim3(512), LDS_TOTAL, stream,
                     hid, owb, (float*)d_out, nullptr, nullptr, nullptr, nullptr, nullptr, out_b);
}

// Round 4
// 593.997 us; speedup vs baseline: 1.0337x; 1.0337x over previous
//
#include <hip/hip_runtime.h>
#include <hip/hip_bf16.h>

// Problem constants
#define MROW 8192   // BATCH
#define DIMK 4096   // DIM (= K of both GEMMs)
#define NCOL 4096   // N_HEADS*HIDDEN = DIM
#define HID  256
#define NH   16
#define SEQL 4096

// GEMM tile geometry: 256x256 tile, BK=32, 8 waves (2M x 4N), ring-of-4 LDS buffers
#define BM 256
#define BN 256
#define BK 32
#define NKT (DIMK / BK)        // 128 K-tiles
#define TILEB (BM * BK * 2)    // 16384 B per A- or B- K-tile
#define LDS_TOTAL (8 * TILEB)  // 131072 B

typedef __attribute__((ext_vector_type(8))) short short8;
typedef __attribute__((ext_vector_type(4))) float f32x4;

__device__ inline ushort f2bf(float f) {
  unsigned u = __float_as_uint(f);
  u += 0x7FFF + ((u >> 16) & 1);   // RNE
  return (ushort)(u >> 16);
}

__device__ inline void gload16(const void* g, void* l) {
  __builtin_amdgcn_global_load_lds(
      (const __attribute__((address_space(1))) void*)g,
      (__attribute__((address_space(3))) void*)l, 16, 0, 0);
}

// fp32 -> bf16, 8 elements/thread, grid-stride
__global__ void cvt_f32_bf16(const float* __restrict__ s, ushort* __restrict__ d, long n8) {
  long stride = (long)gridDim.x * blockDim.x;
  for (long i = (long)blockIdx.x * blockDim.x + threadIdx.x; i < n8; i += stride) {
    const float4* s4 = (const float4*)(s + i * 8);
    float4 a = s4[0], b = s4[1];
    ushort r[8] = {f2bf(a.x), f2bf(a.y), f2bf(a.z), f2bf(a.w),
                   f2bf(b.x), f2bf(b.y), f2bf(b.z), f2bf(b.w)};
    *(uint4*)(d + i * 8) = *(const uint4*)r;
  }
}

// per-output-column coefficients for the GEMM1 epilogue
__global__ void coef_kernel(const float* __restrict__ mix_w, const float* __restrict__ mix_b,
                            const float* __restrict__ decay_value, const float* __restrict__ proj_b,
                            const int* __restrict__ index_p,
                            float* __restrict__ wv, float* __restrict__ cc, float* __restrict__ pb2) {
  int n = blockIdx.x * blockDim.x + threadIdx.x;   // 0..4095
  if (n >= NCOL) return;
  int h = n >> 8;
  int idx = *index_p;
  float w  = mix_w[h * SEQL + idx];
  float bb = mix_b[h * SEQL + idx];
  float dv = fminf(fmaxf(decay_value[h], 0.9f), 1.0f);
  float decay = powf(dv, 0.125f);                  // 1/DECAY_CONSTANT (=8)
  float coef = (h < NH / 2) ? w * decay : decay;
  wv[n]  = w;
  cc[n]  = coef;
  pb2[n] = w * proj_b[n] + bb;
}

// stage one 256x32 bf16 K-tile (A or B) into a linear LDS buffer with
// inverse-swizzled global source (rule 21: linear dest + pre-swizzled src).
// Swizzle: 16B-column c' = c ^ ((row>>1)&3) -> 2-way bank aliasing on ds_read (free, m136).
__device__ inline void stage(const ushort* __restrict__ G, int k0, char* lbase, int tid) {
#pragma unroll
  for (int j = 0; j < 2; ++j) {
    int off = j * 8192 + tid * 16;      // linear LDS byte offset (wave-uniform base + lane*16)
    int row = off >> 6;                 // 64 B per row (32 bf16)
    int c   = (off >> 4) & 3;
    int cs  = c ^ ((row >> 1) & 3);
    gload16(G + (size_t)row * DIMK + k0 + cs * 8, lbase + off);
  }
}

// read one MFMA fragment (16B/lane) from a swizzled K-tile
__device__ inline short8 frag(const char* base, int row, int c) {
  int cs = c ^ ((row >> 1) & 3);
  return *(const short8*)(base + row * 64 + cs * 16);
}

// C = A(MxK) * B^T(NxK), bf16. One barrier per K-tile: 12 ds_reads + 4 stages +
// 32 MFMA free-run per iteration (compiler emits fine-grained lgkmcnt for the
// ds_read->MFMA deps); counted vmcnt keeps 2 K-tiles of prefetch in flight.
// EPI==1: mix -> bf16; EPI==0: +out_b -> f32.
template <int EPI>
__global__ __launch_bounds__(512, 2) void gemm256(
    const ushort* __restrict__ A, const ushort* __restrict__ B,
    float* __restrict__ outf, ushort* __restrict__ outh,
    const float* __restrict__ cache, const float* __restrict__ wv,
    const float* __restrict__ cc, const float* __restrict__ pb2,
    const float* __restrict__ outb) {
  extern __shared__ __align__(16) char smem[];
  char* const Abufs = smem;                 // 4 x 16KB
  char* const Bbufs = smem + 4 * TILEB;     // 4 x 16KB

  const int tid  = threadIdx.x;
  const int lane = tid & 63;
  const int wid  = tid >> 6;
  const int wr = wid >> 2;       // 0..1  (M)
  const int wc = wid & 3;        // 0..3  (N)
  const int r16 = lane & 15;
  const int cq  = lane >> 4;     // 16B column block 0..3

  // XCD-bijective block swizzle (grid = 512, 512 % 8 == 0)
  const int bid = blockIdx.x;
  const int swz = (bid & 7) * 64 + (bid >> 3);
  const int bm = swz >> 4, bn = swz & 15;   // 32 x 16 tiles
  const int m0 = bm * BM, n0 = bn * BN;

  const ushort* Ag = A + (size_t)m0 * DIMK;
  const ushort* Bg = B + (size_t)n0 * DIMK;

  f32x4 acc[8][4] = {};

  // prologue: stage K-tiles 0,1,2 (12 loads/thread); wait until kt0 landed (8 in flight)
#pragma unroll
  for (int kt = 0; kt < 3; ++kt) {
    stage(Ag, kt * BK, Abufs + kt * TILEB, tid);
    stage(Bg, kt * BK, Bbufs + kt * TILEB, tid);
  }
  asm volatile("s_waitcnt vmcnt(8)" ::: "memory");
  __builtin_amdgcn_s_barrier();
  __builtin_amdgcn_sched_barrier(0);

  for (int kt = 0; kt < NKT; ++kt) {
    const char* Ab = Abufs + (kt & 3) * TILEB;
    const char* Bb = Bbufs + (kt & 3) * TILEB;
    const int  ktp = kt + 3;
    const bool do_st = ktp < NKT;

    short8 bfr[4], alo[4], ahi[4];
    // all 12 fragment reads for this K-tile (tile is stable the whole iteration)
#pragma unroll
    for (int ni = 0; ni < 4; ++ni)
      bfr[ni] = frag(Bb, wc * 64 + ni * 16 + r16, cq);
#pragma unroll
    for (int mi = 0; mi < 4; ++mi)
      alo[mi] = frag(Ab, wr * 128 + mi * 16 + r16, cq);
#pragma unroll
    for (int mi = 0; mi < 4; ++mi)
      ahi[mi] = frag(Ab, wr * 128 + 64 + mi * 16 + r16, cq);

    // prefetch K-tile kt+3 (targets ring slot (kt-1)&3, fully consumed last iter)
    if (do_st) {
      stage(Ag, ktp * BK, Abufs + (ktp & 3) * TILEB, tid);
      stage(Bg, ktp * BK, Bbufs + (ktp & 3) * TILEB, tid);
    }

    __builtin_amdgcn_s_setprio(1);
#pragma unroll
    for (int mi = 0; mi < 4; ++mi)
#pragma unroll
      for (int ni = 0; ni < 4; ++ni)
        acc[mi][ni] = __builtin_amdgcn_mfma_f32_16x16x32_bf16(alo[mi], bfr[ni], acc[mi][ni], 0, 0, 0);
#pragma unroll
    for (int mi = 0; mi < 4; ++mi)
#pragma unroll
      for (int ni = 0; ni < 4; ++ni)
        acc[4 + mi][ni] = __builtin_amdgcn_mfma_f32_16x16x32_bf16(ahi[mi], bfr[ni], acc[4 + mi][ni], 0, 0, 0);
    __builtin_amdgcn_s_setprio(0);

    // counted wait: keep 2 K-tiles (8 loads) in flight; guarantee kt+1 landed.
    if (kt < NKT - 3)       asm volatile("s_waitcnt vmcnt(8)" ::: "memory");
    else if (kt == NKT - 3) asm volatile("s_waitcnt vmcnt(4)" ::: "memory");
    else if (kt == NKT - 2) asm volatile("s_waitcnt vmcnt(0)" ::: "memory");
    __builtin_amdgcn_s_barrier();
    // next iteration's ds_reads must not hoist above this barrier (other waves'
    // stage portions for kt+1 are only guaranteed landed after ALL waves' vmcnt).
    __builtin_amdgcn_sched_barrier(0);
  }

  // ---- epilogue
  const int colbase = n0 + wc * 64 + r16;
  const int rowbase = m0 + wr * 128 + cq * 4;

  float wvv[4], ccv[4], pbv[4], obv[4];
#pragma unroll
  for (int ni = 0; ni < 4; ++ni) {
    int n = colbase + ni * 16;
    if (EPI == 1) { wvv[ni] = wv[n]; ccv[ni] = cc[n]; pbv[ni] = pb2[n]; }
    else          { obv[ni] = outb[n]; }
  }

#pragma unroll
  for (int am = 0; am < 8; ++am) {
    int mrow = rowbase + (am >> 2) * 64 + (am & 3) * 16;
#pragma unroll
    for (int ni = 0; ni < 4; ++ni) {
      f32x4 v = acc[am][ni];
      int n = colbase + ni * 16;
#pragma unroll
      for (int r = 0; r < 4; ++r) {
        int m = mrow + r;
        if (EPI == 1) {
          int h = n >> 8, kq = n & 255;
          float val = wvv[ni] * v[r] + ccv[ni] * cache[((size_t)h * MROW + m) * HID + kq] + pbv[ni];
          outh[(size_t)m * NCOL + n] = f2bf(val);
        } else {
          outf[(size_t)m * NCOL + n] = v[r] + obv[ni];
        }
      }
    }
  }
}

extern "C" void kernel_launch(void* const* d_in, const int* in_sizes, int n_in,
                              void* d_out, int out_size, void* d_ws, size_t ws_size,
                              hipStream_t stream) {
  const float* x      = (const float*)d_in[0];
  const float* proj_w = (const float*)d_in[1];
  const float* proj_b = (const float*)d_in[2];
  const float* mix_w  = (const float*)d_in[3];
  const float* mix_b  = (const float*)d_in[4];
  const float* decay  = (const float*)d_in[5];
  const float* cache  = (const float*)d_in[6];
  const float* out_w  = (const float*)d_in[7];
  const float* out_b  = (const float*)d_in[8];
  const int*   index  = (const int*)d_in[9];

  char* ws = (char*)d_ws;
  ushort* xb  = (ushort*)ws;                         // 8192*4096*2 = 64 MiB
  ushort* pwb = (ushort*)(ws + 67108864);            // 32 MiB
  ushort* owb = (ushort*)(ws + 100663296);           // 32 MiB
  ushort* hid = (ushort*)(ws + 134217728);           // 64 MiB
  float*  wv  = (float*)(ws + 201326592);
  float*  cc  = (float*)(ws + 201326592 + 16384);
  float*  pb2 = (float*)(ws + 201326592 + 32768);

  // allow 128 KiB dynamic LDS (host-side attribute set; not a stream op)
  hipFuncSetAttribute((const void*)&gemm256<1>, hipFuncAttributeMaxDynamicSharedMemorySize, LDS_TOTAL);
  hipFuncSetAttribute((const void*)&gemm256<0>, hipFuncAttributeMaxDynamicSharedMemorySize, LDS_TOTAL);

  hipLaunchKernelGGL(cvt_f32_bf16, dim3(2048), dim3(256), 0, stream,
                     x, xb, (long)MROW * DIMK / 8);
  hipLaunchKernelGGL(cvt_f32_bf16, dim3(1024), dim3(256), 0, stream,
                     proj_w, pwb, (long)NCOL * DIMK / 8);
  hipLaunchKernelGGL(cvt_f32_bf16, dim3(1024), dim3(256), 0, stream,
                     out_w, owb, (long)NCOL * DIMK / 8);
  hipLaunchKernelGGL(coef_kernel, dim3(16), dim3(256), 0, stream,
                     mix_w, mix_b, decay, proj_b, index, wv, cc, pb2);

  // GEMM1: hidden = mix(x @ proj_w^T) -> bf16
  hipLaunchKernelGGL((gemm256<1>), dim3((MROW / BM) * (NCOL / BN)), dim3(512), LDS_TOTAL, stream,
                     xb, pwb, nullptr, hid, cache, wv, cc, pb2, nullptr);
  // GEMM2: out = hidden @ out_w^T + out_b -> f32
  hipLaunchKernelGGL((gemm256<0>), dim3((MROW / BM) * (NCOL / BN)), dim3(512), LDS_TOTAL, stream,
                     hid, owb, (float*)d_out, nullptr, nullptr, nullptr, nullptr, nullptr, out_b);
}